// Round 2
// baseline (1798.021 us; speedup 1.0000x reference)
//
#include <hip/hip_runtime.h>
#include <hip/hip_bf16.h>
#include <math.h>

#define EMB 512
#define HEADS 16
#define WS 8
#define BSZ 8
#define HW 64
#define NTOK (HW * HW)
#define EH 32          // EMB / HEADS
#define WN 8           // windows per side
#define M_TOT (BSZ * NTOK)   // 32768 rows in all GEMMs

// ---------------------------------------------------------------------------
// GEMM: Out[m][n] = sum_k X[m][k] * W[n][k] + bias[n]   (X:[M,512], W:[512,512])
// 128x128 tile, BK=16, 256 threads, 8x8 micro-tile (split 4+4 to keep every
// ds_read_b128 within 2 bank-wraps -> conflict-free), reg->LDS double buffer.
// ---------------------------------------------------------------------------
#define BM 128
#define BN 128
#define BK 16

struct GemmBatch {
  const float* X[4];
  const float* W[4];
  const float* Bi[4];
  float*       O[4];
};

__global__ __launch_bounds__(256) void gemm_xwT(GemmBatch P) {
  const int z = blockIdx.z;
  const float* __restrict__ X  = P.X[z];
  const float* __restrict__ W  = P.W[z];
  const float* __restrict__ Bi = P.Bi[z];
  float* __restrict__       O  = P.O[z];

  __shared__ float As[BK][BM + 4];   // transposed: As[k][m], row = 132 floats
  __shared__ float Bs[BK][BN + 4];

  const int tid = threadIdx.x;
  const int tx  = tid & 15;          // output col group (cols tx*4 and 64+tx*4)
  const int ty  = tid >> 4;          // output row group (rows ty*4 and 64+ty*4)
  const int lr  = tid >> 2;          // load row 0..63
  const int lk  = (tid & 3) << 2;    // load k offset {0,4,8,12}

  const size_t m0 = (size_t)blockIdx.x * BM;
  const size_t n0 = (size_t)blockIdx.y * BN;

  const float* Xp = X + m0 * 512 + lk;
  const float* Wp = W + n0 * 512 + lk;

  // prefetch tile 0 into registers
  float4 xa = *(const float4*)&Xp[(size_t)lr * 512];
  float4 xb = *(const float4*)&Xp[(size_t)(lr + 64) * 512];
  float4 wa = *(const float4*)&Wp[(size_t)lr * 512];
  float4 wb = *(const float4*)&Wp[(size_t)(lr + 64) * 512];

  float acc[8][8];
  #pragma unroll
  for (int i = 0; i < 8; ++i)
    #pragma unroll
    for (int j = 0; j < 8; ++j) acc[i][j] = 0.f;

  for (int k0 = 0; k0 < 512; k0 += BK) {
    __syncthreads();   // previous iteration's LDS reads done
    As[lk + 0][lr]      = xa.x; As[lk + 1][lr]      = xa.y;
    As[lk + 2][lr]      = xa.z; As[lk + 3][lr]      = xa.w;
    As[lk + 0][lr + 64] = xb.x; As[lk + 1][lr + 64] = xb.y;
    As[lk + 2][lr + 64] = xb.z; As[lk + 3][lr + 64] = xb.w;
    Bs[lk + 0][lr]      = wa.x; Bs[lk + 1][lr]      = wa.y;
    Bs[lk + 2][lr]      = wa.z; Bs[lk + 3][lr]      = wa.w;
    Bs[lk + 0][lr + 64] = wb.x; Bs[lk + 1][lr + 64] = wb.y;
    Bs[lk + 2][lr + 64] = wb.z; Bs[lk + 3][lr + 64] = wb.w;
    __syncthreads();

    if (k0 + BK < 512) {   // issue next-tile loads; latency hides under compute
      const int ko = k0 + BK;
      xa = *(const float4*)&Xp[(size_t)lr * 512 + ko];
      xb = *(const float4*)&Xp[(size_t)(lr + 64) * 512 + ko];
      wa = *(const float4*)&Wp[(size_t)lr * 512 + ko];
      wb = *(const float4*)&Wp[(size_t)(lr + 64) * 512 + ko];
    }

    #pragma unroll
    for (int kk = 0; kk < BK; ++kk) {
      float a[8], b[8];
      *(float4*)&a[0] = *(const float4*)&As[kk][ty * 4];        // 2-bank-wrap span
      *(float4*)&a[4] = *(const float4*)&As[kk][64 + ty * 4];
      *(float4*)&b[0] = *(const float4*)&Bs[kk][tx * 4];        // 2-way max: free
      *(float4*)&b[4] = *(const float4*)&Bs[kk][64 + tx * 4];
      #pragma unroll
      for (int i = 0; i < 8; ++i)
        #pragma unroll
        for (int j = 0; j < 8; ++j)
          acc[i][j] = fmaf(a[i], b[j], acc[i][j]);
    }
  }

  float bias[8];
  *(float4*)&bias[0] = *(const float4*)&Bi[n0 + tx * 4];
  *(float4*)&bias[4] = *(const float4*)&Bi[n0 + 64 + tx * 4];

  #pragma unroll
  for (int i = 0; i < 8; ++i) {
    const size_t m = m0 + (i < 4 ? ty * 4 + i : 64 + ty * 4 + (i - 4));
    float o[8];
    #pragma unroll
    for (int j = 0; j < 8; ++j) o[j] = acc[i][j] + bias[j];
    *(float4*)&O[m * 512 + n0 + tx * 4]      = *(const float4*)&o[0];
    *(float4*)&O[m * 512 + n0 + 64 + tx * 4] = *(const float4*)&o[4];
  }
}

// ---------------------------------------------------------------------------
// Windowed attention. One block (64 threads) per (b, head, wi, wj).
// Thread t = token q = w1*8+w2 of the window. Roll(-4,-4) folded into loads.
// Input channel for (e, h) = e*16 + h ; output channel = h*32 + e.
// ---------------------------------------------------------------------------
__global__ __launch_bounds__(64) void attn_kernel(
    const float* __restrict__ c,   const float* __restrict__ s,
    const float* __restrict__ vsc, const float* __restrict__ vsh,
    const float* __restrict__ pe,  float* __restrict__ osc, float* __restrict__ osh) {
  __shared__ float Ksh[64][33];    // pad -> 2-way max on writes; reads broadcast
  __shared__ float Vs[64][33];
  __shared__ float Vh[64][33];
  __shared__ float pesh[225];      // 15x15

  const int bid = blockIdx.x;
  const int wj = bid & 7;
  const int wi = (bid >> 3) & 7;
  const int h  = (bid >> 6) & 15;
  const int b  = bid >> 10;

  const int t  = threadIdx.x;      // q index in window
  const int w1 = t >> 3;
  const int w2 = t & 7;

  const int y = (wi * 8 + w1 + 4) & 63;   // roll by -SHIFT
  const int x = (wj * 8 + w2 + 4) & 63;
  const size_t base = ((size_t)b * NTOK + (size_t)y * 64 + x) * EMB + h;

  for (int i = t; i < 225; i += 64) pesh[i] = pe[i];

  float q[32];
  #pragma unroll
  for (int e = 0; e < 32; ++e) {
    Ksh[t][e] = s  [base + e * 16];
    Vs [t][e] = vsc[base + e * 16];
    Vh [t][e] = vsh[base + e * 16];
    q[e]      = c  [base + e * 16];
  }
  __syncthreads();

  const float invs = 0.17677669529663687f;  // 1/sqrt(32)
  const bool rmask = (wi == 7);
  const bool cmask = (wj == 7);

  float sr[64];
  #pragma unroll 4
  for (int k = 0; k < 64; ++k) {
    float d = 0.f;
    #pragma unroll
    for (int e = 0; e < 32; ++e) d = fmaf(q[e], Ksh[k][e], d);
    d *= invs;
    const int ry = (k >> 3) - w1 + 7;
    const int rx = (k & 7) - w2 + 7;
    d += pesh[ry * 15 + rx];
    if (rmask && (((t >> 5) & 1) != ((k >> 5) & 1))) d = -1e30f;
    if (cmask && (((t >> 2) & 1) != ((k >> 2) & 1))) d = -1e30f;
    sr[k] = d;
  }

  float mx = -1e30f;
  #pragma unroll
  for (int k = 0; k < 64; ++k) mx = fmaxf(mx, sr[k]);
  float sum = 0.f;
  #pragma unroll
  for (int k = 0; k < 64; ++k) { sr[k] = expf(sr[k] - mx); sum += sr[k]; }
  const float rs = 1.f / sum;

  float oc[32], oh[32];
  #pragma unroll
  for (int e = 0; e < 32; ++e) { oc[e] = 0.f; oh[e] = 0.f; }
  #pragma unroll 4
  for (int k = 0; k < 64; ++k) {
    const float w = sr[k] * rs;
    #pragma unroll
    for (int e = 0; e < 32; ++e) {
      oc[e] = fmaf(w, Vs[k][e], oc[e]);
      oh[e] = fmaf(w, Vh[k][e], oh[e]);
    }
  }

  // unwindow (no roll-back in reference); out channel = h*32 + e
  const size_t np = (size_t)(wi * 8 + w1) * 64 + (wj * 8 + w2);
  const size_t ob = ((size_t)b * NTOK + np) * EMB + (size_t)h * 32;
  #pragma unroll
  for (int e = 0; e < 32; e += 4)
    *(float4*)&osc[ob + e] = *(const float4*)&oc[e];
  #pragma unroll
  for (int e = 0; e < 32; e += 4)
    *(float4*)&osh[ob + e] = *(const float4*)&oh[e];
}

// ---------------------------------------------------------------------------
extern "C" void kernel_launch(void* const* d_in, const int* in_sizes, int n_in,
                              void* d_out, int out_size, void* d_ws, size_t ws_size,
                              hipStream_t stream) {
  const float* content = (const float*)d_in[0];
  const float* style   = (const float*)d_in[1];
  const float* scalex  = (const float*)d_in[2];
  const float* shiftx  = (const float*)d_in[3];
  const float* W1  = (const float*)d_in[4];  const float* b1  = (const float*)d_in[5];
  const float* W2  = (const float*)d_in[6];  const float* b2  = (const float*)d_in[7];
  const float* Wsc = (const float*)d_in[8];  const float* bsc = (const float*)d_in[9];
  const float* Wsh = (const float*)d_in[10]; const float* bsh = (const float*)d_in[11];
  const float* Wso = (const float*)d_in[12]; const float* bso = (const float*)d_in[13];
  const float* Wsho= (const float*)d_in[14]; const float* bsho= (const float*)d_in[15];
  const float* pos = (const float*)d_in[16];
  float* out = (float*)d_out;

  float* ws = (float*)d_ws;
  const size_t SZ = (size_t)M_TOT * EMB;   // 16,777,216 floats per buffer
  float* c_  = ws;
  float* s_  = ws + SZ;
  float* sc_ = ws + 2 * SZ;
  float* sh_ = ws + 3 * SZ;
  float* oc_ = ws + 4 * SZ;
  float* oh_ = ws + 5 * SZ;

  // 4 input projections in one batched launch
  GemmBatch P1;
  P1.X[0] = content; P1.W[0] = W1;  P1.Bi[0] = b1;  P1.O[0] = c_;
  P1.X[1] = style;   P1.W[1] = W2;  P1.Bi[1] = b2;  P1.O[1] = s_;
  P1.X[2] = scalex;  P1.W[2] = Wsc; P1.Bi[2] = bsc; P1.O[2] = sc_;
  P1.X[3] = shiftx;  P1.W[3] = Wsh; P1.Bi[3] = bsh; P1.O[3] = sh_;
  hipLaunchKernelGGL(gemm_xwT, dim3(M_TOT / BM, EMB / BN, 4), dim3(256), 0, stream, P1);

  hipLaunchKernelGGL(attn_kernel, dim3(BSZ * HEADS * WN * WN), dim3(64), 0, stream,
                     c_, s_, sc_, sh_, pos, oc_, oh_);

  // 2 output projections
  GemmBatch P2;
  P2.X[0] = oc_; P2.W[0] = Wso;  P2.Bi[0] = bso;  P2.O[0] = out;
  P2.X[1] = oh_; P2.W[1] = Wsho; P2.Bi[1] = bsho; P2.O[1] = out + SZ;
  P2.X[2] = oc_; P2.W[2] = Wso;  P2.Bi[2] = bso;  P2.O[2] = out;       // unused (gridDim.z = 2)
  P2.X[3] = oh_; P2.W[3] = Wsho; P2.Bi[3] = bsho; P2.O[3] = out + SZ;  // unused
  hipLaunchKernelGGL(gemm_xwT, dim3(M_TOT / BM, EMB / BN, 2), dim3(256), 0, stream, P2);
}

// Round 3
// 776.873 us; speedup vs baseline: 2.3144x; 2.3144x over previous
//
#include <hip/hip_runtime.h>
#include <hip/hip_bf16.h>
#include <math.h>

#define EMB 512
#define HEADS 16
#define WS 8
#define BSZ 8
#define HW 64
#define NTOK (HW * HW)
#define WN 8
#define M_TOT (BSZ * NTOK)        // 32768
#define NELEM ((size_t)M_TOT * EMB)  // 16,777,216 per activation tensor

typedef _Float16 f16;
typedef _Float16 f16x4 __attribute__((ext_vector_type(4)));
typedef _Float16 f16x8 __attribute__((ext_vector_type(8)));
typedef float f32x4 __attribute__((ext_vector_type(4)));

// ---------------------------------------------------------------------------
// fp32 -> fp16 activation conversion (vectorized, grid-stride)
// ---------------------------------------------------------------------------
struct CvtActs { const float* in[4]; f16* out[4]; };

__global__ __launch_bounds__(256) void cvt_acts(CvtActs P) {
  const float4* __restrict__ in = (const float4*)P.in[blockIdx.z];
  f16x4* __restrict__ out = (f16x4*)P.out[blockIdx.z];
  const int n4 = (int)(NELEM / 4);
  for (int i = blockIdx.x * blockDim.x + threadIdx.x; i < n4;
       i += gridDim.x * blockDim.x) {
    float4 v = in[i];
    f16x4 h = {(f16)v.x, (f16)v.y, (f16)v.z, (f16)v.w};
    out[i] = h;
  }
}

// ---------------------------------------------------------------------------
// weight conversion. z<4: permute rows to head-major (out row h*32+e comes
// from in row e*16+h) and permute bias; z>=4: identity copy.
// ---------------------------------------------------------------------------
struct CvtW { const float* w[6]; const float* b[4]; f16* out[6]; float* bp; };

__global__ __launch_bounds__(128) void cvt_w(CvtW P) {
  const int z = blockIdx.y;
  const int np = blockIdx.x;                       // output row 0..511
  const int src = (z < 4) ? ((np & 31) * 16 + (np >> 5)) : np;
  const float4* __restrict__ in = (const float4*)(P.w[z] + (size_t)src * 512);
  f16x4* __restrict__ out = (f16x4*)(P.out[z] + (size_t)np * 512);
  const int t = threadIdx.x;                       // 128 threads * 4 cols
  float4 v = in[t];
  f16x4 h = {(f16)v.x, (f16)v.y, (f16)v.z, (f16)v.w};
  out[t] = h;
  if (t == 0 && z < 4) P.bp[z * 512 + np] = P.b[z][src];
}

// ---------------------------------------------------------------------------
// f16 MFMA GEMM: O[m][n] = sum_k A[m][k]*B[n][k] + bias[n]
// 128x128 tile, BK=32, 4 waves (2x2), 16x16x32 MFMA, global_load_lds(16B)
// into XOR-swizzled LDS (slot' = q ^ ((row>>1)&3)) -> 2-way max on ds_read_b128.
// ---------------------------------------------------------------------------
struct GemmF16 { const f16* X[4]; const f16* W[4]; const float* Bi[4]; void* O[4]; };

template <typename OutT>
__global__ __launch_bounds__(256) void gemm_mfma(GemmF16 P) {
  const int z = blockIdx.z;
  const f16* __restrict__ A = P.X[z];
  const f16* __restrict__ B = P.W[z];
  const float* __restrict__ Bi = P.Bi[z];
  OutT* __restrict__ O = (OutT*)P.O[z];

  __shared__ f16 lds[2][2][128 * 32];   // [dbuf][A/B][row*32 + col], 32 KiB

  const int tid = threadIdx.x;
  const int lane = tid & 63;
  const int wid = tid >> 6;
  const int wr = wid >> 1, wc = wid & 1;
  const size_t m0 = (size_t)blockIdx.x * 128;
  const size_t n0 = (size_t)blockIdx.y * 128;

  const f16* Ag = A + m0 * 512;
  const f16* Bg = B + n0 * 512;

  // staging decomposition: lane -> (row-in-16, slot); inverse-swizzled source
  const int rl = lane >> 2;
  const int qs = (lane & 3) ^ ((rl >> 1) & 3);
  const size_t goff = (size_t)rl * 512 + (size_t)qs * 8;

  const int c = lane & 15;
  const int g = lane >> 4;

  // fragment ds_read offsets (f16 units), swizzled
  int aoff[4], boff[4];
  #pragma unroll
  for (int i = 0; i < 4; ++i) {
    const int rowa = wr * 64 + i * 16 + c;
    aoff[i] = rowa * 32 + ((g ^ ((rowa >> 1) & 3)) * 8);
    const int rowb = wc * 64 + i * 16 + c;
    boff[i] = rowb * 32 + ((g ^ ((rowb >> 1) & 3)) * 8);
  }

  f32x4 acc[4][4];
  #pragma unroll
  for (int i = 0; i < 4; ++i)
    #pragma unroll
    for (int j = 0; j < 4; ++j) acc[i][j] = (f32x4){0.f, 0.f, 0.f, 0.f};

#define STAGE(buf, k0) do {                                                    \
    _Pragma("unroll")                                                          \
    for (int ii = 0; ii < 2; ++ii) {                                           \
      const int s = wid * 2 + ii;                                              \
      const f16* ga = Ag + (size_t)s * 16 * 512 + (size_t)(k0) + goff;         \
      const f16* gb = Bg + (size_t)s * 16 * 512 + (size_t)(k0) + goff;         \
      __builtin_amdgcn_global_load_lds(                                        \
          (const __attribute__((address_space(1))) void*)ga,                   \
          (__attribute__((address_space(3))) void*)&lds[buf][0][s * 512],      \
          16, 0, 0);                                                           \
      __builtin_amdgcn_global_load_lds(                                        \
          (const __attribute__((address_space(1))) void*)gb,                   \
          (__attribute__((address_space(3))) void*)&lds[buf][1][s * 512],      \
          16, 0, 0);                                                           \
    } } while (0)

  STAGE(0, 0);
  __syncthreads();   // drains vmcnt -> tile 0 resident

  for (int t = 0; t < 16; ++t) {
    const int cur = t & 1;
    if (t < 15) STAGE(cur ^ 1, (t + 1) * 32);
    f16x8 af[4], bf[4];
    #pragma unroll
    for (int i = 0; i < 4; ++i) {
      af[i] = *(const f16x8*)&lds[cur][0][aoff[i]];
      bf[i] = *(const f16x8*)&lds[cur][1][boff[i]];
    }
    #pragma unroll
    for (int mi = 0; mi < 4; ++mi)
      #pragma unroll
      for (int ni = 0; ni < 4; ++ni)
        acc[mi][ni] = __builtin_amdgcn_mfma_f32_16x16x32_f16(
            af[mi], bf[ni], acc[mi][ni], 0, 0, 0);
    __syncthreads();   // reads done + staged tile drained
  }
#undef STAGE

  // epilogue: D col = lane&15, row = (lane>>4)*4 + r  [m89-verified layout]
  const int col_base = (int)n0 + wc * 64;
  const int row_base = (int)m0 + wr * 64 + g * 4;
  float bv[4];
  #pragma unroll
  for (int ni = 0; ni < 4; ++ni) bv[ni] = Bi[col_base + ni * 16 + c];
  #pragma unroll
  for (int mi = 0; mi < 4; ++mi)
    #pragma unroll
    for (int ni = 0; ni < 4; ++ni)
      #pragma unroll
      for (int r = 0; r < 4; ++r) {
        const size_t row = (size_t)(row_base + mi * 16 + r);
        O[row * 512 + col_base + ni * 16 + c] = (OutT)(acc[mi][ni][r] + bv[ni]);
      }
}

// ---------------------------------------------------------------------------
// Windowed attention, head-major f16 inputs (channel = h*32+e), f16 outputs.
// One wave per (b, head, wi, wj); roll(-4,-4) folded into loads; masks analytic.
// All k-loops FULLY unrolled (sr[64] must stay in registers, rule #20).
// ---------------------------------------------------------------------------
__global__ __launch_bounds__(64) void attn_kernel(
    const f16* __restrict__ cq, const f16* __restrict__ ck,
    const f16* __restrict__ vs, const f16* __restrict__ vh,
    const float* __restrict__ pe, f16* __restrict__ osc, f16* __restrict__ osh) {
  __shared__ float Ksh[64][33];
  __shared__ float Vs[64][33];
  __shared__ float Vh[64][33];
  __shared__ float pesh[225];

  const int bid = blockIdx.x;
  const int wj = bid & 7;
  const int wi = (bid >> 3) & 7;
  const int h  = (bid >> 6) & 15;
  const int b  = bid >> 10;

  const int t  = threadIdx.x;
  const int w1 = t >> 3;
  const int w2 = t & 7;

  const int y = (wi * 8 + w1 + 4) & 63;
  const int x = (wj * 8 + w2 + 4) & 63;
  const size_t base = ((size_t)b * NTOK + (size_t)y * 64 + x) * EMB + (size_t)h * 32;

  for (int i = t; i < 225; i += 64) pesh[i] = pe[i];

  float q[32];
  {
    const f16x8* qp = (const f16x8*)(cq + base);
    const f16x8* kp = (const f16x8*)(ck + base);
    const f16x8* sp = (const f16x8*)(vs + base);
    const f16x8* hp = (const f16x8*)(vh + base);
    #pragma unroll
    for (int jj = 0; jj < 4; ++jj) {
      f16x8 qv = qp[jj], kv = kp[jj], sv = sp[jj], hv = hp[jj];
      #pragma unroll
      for (int e = 0; e < 8; ++e) {
        q[jj * 8 + e]      = (float)qv[e];
        Ksh[t][jj * 8 + e] = (float)kv[e];
        Vs [t][jj * 8 + e] = (float)sv[e];
        Vh [t][jj * 8 + e] = (float)hv[e];
      }
    }
  }
  __syncthreads();

  const float invs = 0.17677669529663687f;  // 1/sqrt(32)
  const bool rmask = (wi == 7);
  const bool cmask = (wj == 7);

  float sr[64];
  #pragma unroll
  for (int k = 0; k < 64; ++k) {
    float d = 0.f;
    #pragma unroll
    for (int e = 0; e < 32; ++e) d = fmaf(q[e], Ksh[k][e], d);
    d *= invs;
    const int ry = (k >> 3) - w1 + 7;
    const int rx = (k & 7) - w2 + 7;
    d += pesh[ry * 15 + rx];
    if (rmask && (((t >> 5) & 1) != ((k >> 5) & 1))) d = -1e30f;
    if (cmask && (((t >> 2) & 1) != ((k >> 2) & 1))) d = -1e30f;
    sr[k] = d;
  }

  float mx = -1e30f;
  #pragma unroll
  for (int k = 0; k < 64; ++k) mx = fmaxf(mx, sr[k]);
  float sum = 0.f;
  #pragma unroll
  for (int k = 0; k < 64; ++k) { sr[k] = __expf(sr[k] - mx); sum += sr[k]; }
  const float rs = 1.f / sum;

  float oc[32], oh[32];
  #pragma unroll
  for (int e = 0; e < 32; ++e) { oc[e] = 0.f; oh[e] = 0.f; }
  #pragma unroll
  for (int k = 0; k < 64; ++k) {
    const float w = sr[k] * rs;
    #pragma unroll
    for (int e = 0; e < 32; ++e) {
      oc[e] = fmaf(w, Vs[k][e], oc[e]);
      oh[e] = fmaf(w, Vh[k][e], oh[e]);
    }
  }

  const size_t np = (size_t)(wi * 8 + w1) * 64 + (wj * 8 + w2);
  const size_t ob = ((size_t)b * NTOK + np) * EMB + (size_t)h * 32;
  f16x8* oscp = (f16x8*)(osc + ob);
  f16x8* oshp = (f16x8*)(osh + ob);
  #pragma unroll
  for (int jj = 0; jj < 4; ++jj) {
    f16x8 a, bb;
    #pragma unroll
    for (int e = 0; e < 8; ++e) { a[e] = (f16)oc[jj * 8 + e]; bb[e] = (f16)oh[jj * 8 + e]; }
    oscp[jj] = a;
    oshp[jj] = bb;
  }
}

// ---------------------------------------------------------------------------
extern "C" void kernel_launch(void* const* d_in, const int* in_sizes, int n_in,
                              void* d_out, int out_size, void* d_ws, size_t ws_size,
                              hipStream_t stream) {
  const float* content = (const float*)d_in[0];
  const float* style   = (const float*)d_in[1];
  const float* scalex  = (const float*)d_in[2];
  const float* shiftx  = (const float*)d_in[3];
  const float* W1  = (const float*)d_in[4];  const float* b1  = (const float*)d_in[5];
  const float* W2  = (const float*)d_in[6];  const float* b2  = (const float*)d_in[7];
  const float* Wsc = (const float*)d_in[8];  const float* bsc = (const float*)d_in[9];
  const float* Wsh = (const float*)d_in[10]; const float* bsh = (const float*)d_in[11];
  const float* Wso = (const float*)d_in[12]; const float* bso = (const float*)d_in[13];
  const float* Wsho= (const float*)d_in[14]; const float* bsho= (const float*)d_in[15];
  const float* pos = (const float*)d_in[16];
  float* out = (float*)d_out;

  // workspace layout (f16-heavy): 4 Xh + 6 Wh + bias + 4 proj + 2 attn-out
  f16* Xh = (f16*)d_ws;                       // 4 x NELEM
  f16* Wh = Xh + 4 * NELEM;                   // 6 x 262144
  float* bp = (float*)(Wh + 6 * 262144);      // 4 x 512
  f16* Ph = (f16*)(bp + 4 * 512);             // 4 x NELEM (c,s,sc,sh head-major)
  f16* Oh = Ph + 4 * NELEM;                   // 2 x NELEM (oc, oh)

  // 1) convert activations
  CvtActs CA;
  CA.in[0] = content; CA.in[1] = style; CA.in[2] = scalex; CA.in[3] = shiftx;
  for (int i = 0; i < 4; ++i) CA.out[i] = Xh + (size_t)i * NELEM;
  hipLaunchKernelGGL(cvt_acts, dim3(2048, 1, 4), dim3(256), 0, stream, CA);

  // 2) convert weights (P1 rows permuted to head-major) + biases
  CvtW CW;
  CW.w[0] = W1; CW.w[1] = W2; CW.w[2] = Wsc; CW.w[3] = Wsh; CW.w[4] = Wso; CW.w[5] = Wsho;
  CW.b[0] = b1; CW.b[1] = b2; CW.b[2] = bsc; CW.b[3] = bsh;
  for (int i = 0; i < 6; ++i) CW.out[i] = Wh + (size_t)i * 262144;
  CW.bp = bp;
  hipLaunchKernelGGL(cvt_w, dim3(512, 6), dim3(128), 0, stream, CW);

  // 3) input projections (f16 out, head-major channels)
  GemmF16 P1;
  for (int i = 0; i < 4; ++i) {
    P1.X[i] = Xh + (size_t)i * NELEM;
    P1.W[i] = Wh + (size_t)i * 262144;
    P1.Bi[i] = bp + i * 512;
    P1.O[i] = Ph + (size_t)i * NELEM;
  }
  hipLaunchKernelGGL(gemm_mfma<f16>, dim3(M_TOT / 128, EMB / 128, 4), dim3(256), 0,
                     stream, P1);

  // 4) attention
  hipLaunchKernelGGL(attn_kernel, dim3(BSZ * HEADS * WN * WN), dim3(64), 0, stream,
                     Ph, Ph + NELEM, Ph + 2 * NELEM, Ph + 3 * NELEM, pos,
                     Oh, Oh + NELEM);

  // 5) output projections (fp32 out -> d_out)
  GemmF16 P2;
  P2.X[0] = Oh;          P2.W[0] = Wh + 4 * 262144; P2.Bi[0] = bso;  P2.O[0] = out;
  P2.X[1] = Oh + NELEM;  P2.W[1] = Wh + 5 * 262144; P2.Bi[1] = bsho; P2.O[1] = out + NELEM;
  P2.X[2] = P2.X[0]; P2.W[2] = P2.W[0]; P2.Bi[2] = P2.Bi[0]; P2.O[2] = P2.O[0];
  P2.X[3] = P2.X[1]; P2.W[3] = P2.W[1]; P2.Bi[3] = P2.Bi[1]; P2.O[3] = P2.O[1];
  hipLaunchKernelGGL(gemm_mfma<float>, dim3(M_TOT / 128, EMB / 128, 2), dim3(256), 0,
                     stream, P2);
}

// Round 5
// 760.424 us; speedup vs baseline: 2.3645x; 1.0216x over previous
//
#include <hip/hip_runtime.h>
#include <hip/hip_bf16.h>
#include <math.h>

#define EMB 512
#define HEADS 16
#define WS 8
#define BSZ 8
#define HW 64
#define NTOK (HW * HW)
#define WN 8
#define M_TOT (BSZ * NTOK)           // 32768
#define NELEM ((size_t)M_TOT * EMB)  // 16,777,216 per activation tensor

typedef _Float16 f16;
typedef _Float16 f16x4 __attribute__((ext_vector_type(4)));
typedef _Float16 f16x8 __attribute__((ext_vector_type(8)));
typedef float f32x4 __attribute__((ext_vector_type(4)));

// ---------------------------------------------------------------------------
// weight conversion. z<4: permute rows to head-major (out row h*32+e comes
// from in row e*16+h) and permute bias; z>=4: identity copy.
// ---------------------------------------------------------------------------
struct CvtW { const float* w[6]; const float* b[4]; f16* out[6]; float* bp; };

__global__ __launch_bounds__(128) void cvt_w(CvtW P) {
  const int z = blockIdx.y;
  const int np = blockIdx.x;                       // output row 0..511
  const int src = (z < 4) ? ((np & 31) * 16 + (np >> 5)) : np;
  const float4* __restrict__ in = (const float4*)(P.w[z] + (size_t)src * 512);
  f16x4* __restrict__ out = (f16x4*)(P.out[z] + (size_t)np * 512);
  const int t = threadIdx.x;                       // 128 threads * 4 cols
  float4 v = in[t];
  f16x4 h = {(f16)v.x, (f16)v.y, (f16)v.z, (f16)v.w};
  out[t] = h;
  if (t == 0 && z < 4) P.bp[z * 512 + np] = P.b[z][src];
}

// ---------------------------------------------------------------------------
// f16 MFMA GEMM: O[m][n] = sum_k A[m][k]*B[n][k] + bias[n]
// 128x128 tile, BK=32, 4 waves (2x2), 16x16x32 MFMA.
// B always staged via global_load_lds(16B). A path:
//   CVT_A=true : A is fp32; reg-stage (load dwordx4 -> cvt -> ds_write after
//                MFMA, T14-style) -- folds the fp32->f16 conversion pass in.
//   CVT_A=false: A is f16; global_load_lds like B.
// LDS slot swizzle slot' = q ^ ((row>>1)&3), matched on stage & read.
// ---------------------------------------------------------------------------
struct GemmF16 { const void* X[4]; const f16* W[4]; const float* Bi[4]; void* O[4]; };

template <bool CVT_A, typename OutT>
__global__ __launch_bounds__(256) void gemm_mfma(GemmF16 P) {
  const int z = blockIdx.z;
  const f16* __restrict__ B = P.W[z];
  const float* __restrict__ Bi = P.Bi[z];
  OutT* __restrict__ O = (OutT*)P.O[z];

  __shared__ f16 lds[2][2][128 * 32];   // [dbuf][A/B][row*32 + col], 32 KiB

  const int tid = threadIdx.x;
  const int lane = tid & 63;
  const int wid = tid >> 6;
  const int wr = wid >> 1, wc = wid & 1;
  const size_t m0 = (size_t)blockIdx.x * 128;
  const size_t n0 = (size_t)blockIdx.y * 128;

  const f16*  Ag16 = CVT_A ? (const f16*)nullptr : ((const f16*)P.X[z] + m0 * 512);
  const float* Ag32 = CVT_A ? ((const float*)P.X[z] + m0 * 512) : (const float*)nullptr;
  const f16* Bg = B + n0 * 512;

  // staging decomposition: lane -> (row-in-16 rl, k-chunk); inverse-swizzled src
  const int rl = lane >> 2;
  const int qs = (lane & 3) ^ ((rl >> 1) & 3);
  const size_t goff16 = (size_t)rl * 512 + (size_t)qs * 8;

  const int c = lane & 15;
  const int g = lane >> 4;

  // fragment ds_read offsets (f16 units), swizzled
  int aoff[4], boff[4];
  #pragma unroll
  for (int i = 0; i < 4; ++i) {
    const int rowa = wr * 64 + i * 16 + c;
    aoff[i] = rowa * 32 + ((g ^ ((rowa >> 1) & 3)) * 8);
    const int rowb = wc * 64 + i * 16 + c;
    boff[i] = rowb * 32 + ((g ^ ((rowb >> 1) & 3)) * 8);
  }

  f32x4 acc[4][4];
  #pragma unroll
  for (int i = 0; i < 4; ++i)
    #pragma unroll
    for (int j = 0; j < 4; ++j) acc[i][j] = (f32x4){0.f, 0.f, 0.f, 0.f};

  float4 areg[2][2];   // CVT_A in-flight A (2 s-blocks x 8 floats)

#define LOAD_A32(k0) do { if (CVT_A) {                                         \
    _Pragma("unroll")                                                          \
    for (int ii = 0; ii < 2; ++ii) {                                           \
      const int s = wid * 2 + ii;                                              \
      const float* ga = Ag32 + (size_t)(s * 16 + rl) * 512 + (size_t)(k0)      \
                        + (size_t)qs * 8;                                      \
      areg[ii][0] = *(const float4*)ga;                                        \
      areg[ii][1] = *(const float4*)(ga + 4);                                  \
    } } } while (0)

#define WRITE_A(buf) do { if (CVT_A) {                                         \
    _Pragma("unroll")                                                          \
    for (int ii = 0; ii < 2; ++ii) {                                           \
      const int s = wid * 2 + ii;                                              \
      const float* ap = (const float*)&areg[ii][0];                            \
      f16x8 hv;                                                                \
      _Pragma("unroll")                                                        \
      for (int j = 0; j < 8; ++j) hv[j] = (f16)ap[j];                          \
      *(f16x8*)&lds[buf][0][(size_t)s * 512 + (size_t)lane * 8] = hv;          \
    } } } while (0)

#define STAGE_A16(buf, k0) do { if (!CVT_A) {                                  \
    _Pragma("unroll")                                                          \
    for (int ii = 0; ii < 2; ++ii) {                                           \
      const int s = wid * 2 + ii;                                              \
      const f16* ga = Ag16 + (size_t)s * 16 * 512 + (size_t)(k0) + goff16;     \
      __builtin_amdgcn_global_load_lds(                                        \
          (const __attribute__((address_space(1))) void*)ga,                   \
          (__attribute__((address_space(3))) void*)&lds[buf][0][s * 512],      \
          16, 0, 0);                                                           \
    } } } while (0)

#define STAGE_B(buf, k0) do {                                                  \
    _Pragma("unroll")                                                          \
    for (int ii = 0; ii < 2; ++ii) {                                           \
      const int s = wid * 2 + ii;                                              \
      const f16* gb = Bg + (size_t)s * 16 * 512 + (size_t)(k0) + goff16;       \
      __builtin_amdgcn_global_load_lds(                                        \
          (const __attribute__((address_space(1))) void*)gb,                   \
          (__attribute__((address_space(3))) void*)&lds[buf][1][s * 512],      \
          16, 0, 0);                                                           \
    } } while (0)

  // prologue: tile 0
  LOAD_A32(0); STAGE_A16(0, 0); STAGE_B(0, 0); WRITE_A(0);
  __syncthreads();

  for (int t = 0; t < 16; ++t) {
    const int cur = t & 1;
    if (t < 15) { LOAD_A32((t + 1) * 32); STAGE_A16(cur ^ 1, (t + 1) * 32);
                  STAGE_B(cur ^ 1, (t + 1) * 32); }
    f16x8 af[4], bf[4];
    #pragma unroll
    for (int i = 0; i < 4; ++i) {
      af[i] = *(const f16x8*)&lds[cur][0][aoff[i]];
      bf[i] = *(const f16x8*)&lds[cur][1][boff[i]];
    }
    #pragma unroll
    for (int mi = 0; mi < 4; ++mi)
      #pragma unroll
      for (int ni = 0; ni < 4; ++ni)
        acc[mi][ni] = __builtin_amdgcn_mfma_f32_16x16x32_f16(
            af[mi], bf[ni], acc[mi][ni], 0, 0, 0);
    if (t < 15) WRITE_A(cur ^ 1);   // ds_write after MFMA: loads covered by MFMA
    __syncthreads();
  }
#undef LOAD_A32
#undef WRITE_A
#undef STAGE_A16
#undef STAGE_B

  // epilogue: D col = lane&15, row = (lane>>4)*4 + r  [m89-verified layout]
  const int col_base = (int)n0 + wc * 64;
  const int row_base = (int)m0 + wr * 64 + g * 4;
  float bv[4];
  #pragma unroll
  for (int ni = 0; ni < 4; ++ni) bv[ni] = Bi[col_base + ni * 16 + c];
  #pragma unroll
  for (int mi = 0; mi < 4; ++mi)
    #pragma unroll
    for (int ni = 0; ni < 4; ++ni)
      #pragma unroll
      for (int r = 0; r < 4; ++r) {
        const size_t row = (size_t)(row_base + mi * 16 + r);
        O[row * 512 + col_base + ni * 16 + c] = (OutT)(acc[mi][ni][r] + bv[ni]);
      }
}

// ---------------------------------------------------------------------------
// Windowed attention, head-major f16 inputs (channel = h*32+e), f16 outputs.
// One wave per (b, head, wi, wj). K/Vs/Vh in LDS as f16, rows padded to 40
// (80 B: bank start (20t+4jj)%32 -> exactly 8 dwords/bank per b128 write =
// conflict-free; reads are uniform-address broadcasts). fp32 scores in regs.
// ---------------------------------------------------------------------------
#define LROW 40
__global__ __launch_bounds__(64) void attn_kernel(
    const f16* __restrict__ cq, const f16* __restrict__ ck,
    const f16* __restrict__ vs, const f16* __restrict__ vh,
    const float* __restrict__ pe, f16* __restrict__ osc, f16* __restrict__ osh) {
  __shared__ f16 Ksh[64][LROW];
  __shared__ f16 Vsh[64][LROW];
  __shared__ f16 Hsh[64][LROW];
  __shared__ float pesh[225];

  const int bid = blockIdx.x;
  const int wj = bid & 7;
  const int wi = (bid >> 3) & 7;
  const int h  = (bid >> 6) & 15;
  const int b  = bid >> 10;

  const int t  = threadIdx.x;      // q index in window
  const int w1 = t >> 3;
  const int w2 = t & 7;

  const int y = (wi * 8 + w1 + 4) & 63;   // roll by -SHIFT
  const int x = (wj * 8 + w2 + 4) & 63;
  const size_t base = ((size_t)b * NTOK + (size_t)y * 64 + x) * EMB + (size_t)h * 32;

  for (int i = t; i < 225; i += 64) pesh[i] = pe[i];

  f16x8 q8[4];
  #pragma unroll
  for (int jj = 0; jj < 4; ++jj) {
    q8[jj] = *(const f16x8*)(cq + base + jj * 8);
    *(f16x8*)&Ksh[t][jj * 8] = *(const f16x8*)(ck + base + jj * 8);
    *(f16x8*)&Vsh[t][jj * 8] = *(const f16x8*)(vs + base + jj * 8);
    *(f16x8*)&Hsh[t][jj * 8] = *(const f16x8*)(vh + base + jj * 8);
  }
  __syncthreads();

  const float invs = 0.17677669529663687f;  // 1/sqrt(32)
  const bool rmask = (wi == 7);
  const bool cmask = (wj == 7);

  float sr[64];
  #pragma unroll
  for (int k = 0; k < 64; ++k) {
    float d = 0.f;
    #pragma unroll
    for (int jj = 0; jj < 4; ++jj) {
      const f16x8 kv = *(const f16x8*)&Ksh[k][jj * 8];
      #pragma unroll
      for (int e = 0; e < 8; ++e)
        d = fmaf((float)q8[jj][e], (float)kv[e], d);   // v_fma_mix_f32
    }
    d *= invs;
    const int ry = (k >> 3) - w1 + 7;
    const int rx = (k & 7) - w2 + 7;
    d += pesh[ry * 15 + rx];
    if (rmask && (((t >> 5) & 1) != ((k >> 5) & 1))) d = -1e30f;
    if (cmask && (((t >> 2) & 1) != ((k >> 2) & 1))) d = -1e30f;
    sr[k] = d;
  }

  float mx = -1e30f;
  #pragma unroll
  for (int k = 0; k < 64; ++k) mx = fmaxf(mx, sr[k]);
  float sum = 0.f;
  #pragma unroll
  for (int k = 0; k < 64; ++k) { sr[k] = __expf(sr[k] - mx); sum += sr[k]; }
  const float rs = 1.f / sum;
  #pragma unroll
  for (int k = 0; k < 64; ++k) sr[k] *= rs;

  const size_t np = (size_t)(wi * 8 + w1) * 64 + (wj * 8 + w2);
  const size_t ob = ((size_t)b * NTOK + np) * EMB + (size_t)h * 32;

  // PV in two e-halves (16 ch each) to cap accumulator registers
  #pragma unroll
  for (int hh = 0; hh < 2; ++hh) {
    float oc[16], oh2[16];
    #pragma unroll
    for (int e = 0; e < 16; ++e) { oc[e] = 0.f; oh2[e] = 0.f; }
    #pragma unroll
    for (int k = 0; k < 64; ++k) {
      const float w = sr[k];
      const f16x8 a0 = *(const f16x8*)&Vsh[k][hh * 16];
      const f16x8 a1 = *(const f16x8*)&Vsh[k][hh * 16 + 8];
      const f16x8 b0 = *(const f16x8*)&Hsh[k][hh * 16];
      const f16x8 b1 = *(const f16x8*)&Hsh[k][hh * 16 + 8];
      #pragma unroll
      for (int e = 0; e < 8; ++e) {
        oc[e]      = fmaf(w, (float)a0[e], oc[e]);
        oc[e + 8]  = fmaf(w, (float)a1[e], oc[e + 8]);
        oh2[e]     = fmaf(w, (float)b0[e], oh2[e]);
        oh2[e + 8] = fmaf(w, (float)b1[e], oh2[e + 8]);
      }
    }
    f16x8 s0, s1, t0, t1;
    #pragma unroll
    for (int e = 0; e < 8; ++e) {
      s0[e] = (f16)oc[e];  s1[e] = (f16)oc[e + 8];
      t0[e] = (f16)oh2[e]; t1[e] = (f16)oh2[e + 8];
    }
    *(f16x8*)(osc + ob + hh * 16)     = s0;
    *(f16x8*)(osc + ob + hh * 16 + 8) = s1;
    *(f16x8*)(osh + ob + hh * 16)     = t0;
    *(f16x8*)(osh + ob + hh * 16 + 8) = t1;
  }
}

// ---------------------------------------------------------------------------
extern "C" void kernel_launch(void* const* d_in, const int* in_sizes, int n_in,
                              void* d_out, int out_size, void* d_ws, size_t ws_size,
                              hipStream_t stream) {
  const float* content = (const float*)d_in[0];
  const float* style   = (const float*)d_in[1];
  const float* scalex  = (const float*)d_in[2];
  const float* shiftx  = (const float*)d_in[3];
  const float* W1  = (const float*)d_in[4];  const float* b1  = (const float*)d_in[5];
  const float* W2  = (const float*)d_in[6];  const float* b2  = (const float*)d_in[7];
  const float* Wsc = (const float*)d_in[8];  const float* bsc = (const float*)d_in[9];
  const float* Wsh = (const float*)d_in[10]; const float* bsh = (const float*)d_in[11];
  const float* Wso = (const float*)d_in[12]; const float* bso = (const float*)d_in[13];
  const float* Wsho= (const float*)d_in[14]; const float* bsho= (const float*)d_in[15];
  const float* pos = (const float*)d_in[16];
  float* out = (float*)d_out;

  // workspace: Wh(6x262144 f16) | bp(2048 f32) | Ph(4xNELEM f16) | Oh(2xNELEM f16)
  f16* Wh = (f16*)d_ws;
  float* bp = (float*)(Wh + 6 * 262144);
  f16* Ph = (f16*)(bp + 2048);
  f16* Oh = Ph + 4 * NELEM;

  // 1) convert weights (P1 rows permuted to head-major) + biases
  CvtW CW;
  CW.w[0] = W1; CW.w[1] = W2; CW.w[2] = Wsc; CW.w[3] = Wsh; CW.w[4] = Wso; CW.w[5] = Wsho;
  CW.b[0] = b1; CW.b[1] = b2; CW.b[2] = bsc; CW.b[3] = bsh;
  for (int i = 0; i < 6; ++i) CW.out[i] = Wh + (size_t)i * 262144;
  CW.bp = bp;
  hipLaunchKernelGGL(cvt_w, dim3(512, 6), dim3(128), 0, stream, CW);

  // 2) input projections: fp32 A converted in-staging, f16 head-major out
  GemmF16 P1;
  P1.X[0] = content; P1.X[1] = style; P1.X[2] = scalex; P1.X[3] = shiftx;
  for (int i = 0; i < 4; ++i) {
    P1.W[i] = Wh + (size_t)i * 262144;
    P1.Bi[i] = bp + i * 512;
    P1.O[i] = Ph + (size_t)i * NELEM;
  }
  hipLaunchKernelGGL(HIP_KERNEL_NAME(gemm_mfma<true, f16>),
                     dim3(M_TOT / 128, EMB / 128, 4), dim3(256), 0, stream, P1);

  // 3) attention
  hipLaunchKernelGGL(attn_kernel, dim3(BSZ * HEADS * WN * WN), dim3(64), 0, stream,
                     Ph, Ph + NELEM, Ph + 2 * NELEM, Ph + 3 * NELEM, pos,
                     Oh, Oh + NELEM);

  // 4) output projections (f16 A via global_load_lds, fp32 out -> d_out)
  GemmF16 P2;
  P2.X[0] = Oh;          P2.W[0] = Wh + 4 * 262144; P2.Bi[0] = bso;  P2.O[0] = out;
  P2.X[1] = Oh + NELEM;  P2.W[1] = Wh + 5 * 262144; P2.Bi[1] = bsho; P2.O[1] = out + NELEM;
  P2.X[2] = P2.X[0]; P2.W[2] = P2.W[0]; P2.Bi[2] = P2.Bi[0]; P2.O[2] = P2.O[0];
  P2.X[3] = P2.X[1]; P2.W[3] = P2.W[1]; P2.Bi[3] = P2.Bi[1]; P2.O[3] = P2.O[1];
  hipLaunchKernelGGL(HIP_KERNEL_NAME(gemm_mfma<false, float>),
                     dim3(M_TOT / 128, EMB / 128, 2), dim3(256), 0, stream, P2);
}

// Round 6
// 523.682 us; speedup vs baseline: 3.4334x; 1.4521x over previous
//
#include <hip/hip_runtime.h>
#include <hip/hip_bf16.h>
#include <math.h>

#define EMB 512
#define HEADS 16
#define WS 8
#define BSZ 8
#define HW 64
#define NTOK (HW * HW)
#define WN 8
#define M_TOT (BSZ * NTOK)           // 32768
#define NELEM ((size_t)M_TOT * EMB)  // 16,777,216 per activation tensor

typedef _Float16 f16;
typedef _Float16 f16x4 __attribute__((ext_vector_type(4)));
typedef _Float16 f16x8 __attribute__((ext_vector_type(8)));
typedef float f32x4 __attribute__((ext_vector_type(4)));

// ---------------------------------------------------------------------------
// weight conversion. z<4: permute rows to head-major (out row h*32+e comes
// from in row e*16+h) and permute bias; z>=4: identity copy.
// ---------------------------------------------------------------------------
struct CvtW { const float* w[6]; const float* b[4]; f16* out[6]; float* bp; };

__global__ __launch_bounds__(128) void cvt_w(CvtW P) {
  const int z = blockIdx.y;
  const int np = blockIdx.x;                       // output row 0..511
  const int src = (z < 4) ? ((np & 31) * 16 + (np >> 5)) : np;
  const float4* __restrict__ in = (const float4*)(P.w[z] + (size_t)src * 512);
  f16x4* __restrict__ out = (f16x4*)(P.out[z] + (size_t)np * 512);
  const int t = threadIdx.x;                       // 128 threads * 4 cols
  float4 v = in[t];
  f16x4 h = {(f16)v.x, (f16)v.y, (f16)v.z, (f16)v.w};
  out[t] = h;
  if (t == 0 && z < 4) P.bp[z * 512 + np] = P.b[z][src];
}

// ---------------------------------------------------------------------------
// f16 MFMA GEMM: O[m][n] = sum_k A[m][k]*B[n][k] + bias[n]   (unchanged)
// ---------------------------------------------------------------------------
struct GemmF16 { const void* X[4]; const f16* W[4]; const float* Bi[4]; void* O[4]; };

template <bool CVT_A, typename OutT>
__global__ __launch_bounds__(256) void gemm_mfma(GemmF16 P) {
  const int z = blockIdx.z;
  const f16* __restrict__ B = P.W[z];
  const float* __restrict__ Bi = P.Bi[z];
  OutT* __restrict__ O = (OutT*)P.O[z];

  __shared__ f16 lds[2][2][128 * 32];   // [dbuf][A/B][row*32 + col], 32 KiB

  const int tid = threadIdx.x;
  const int lane = tid & 63;
  const int wid = tid >> 6;
  const int wr = wid >> 1, wc = wid & 1;
  const size_t m0 = (size_t)blockIdx.x * 128;
  const size_t n0 = (size_t)blockIdx.y * 128;

  const f16*  Ag16 = CVT_A ? (const f16*)nullptr : ((const f16*)P.X[z] + m0 * 512);
  const float* Ag32 = CVT_A ? ((const float*)P.X[z] + m0 * 512) : (const float*)nullptr;
  const f16* Bg = B + n0 * 512;

  const int rl = lane >> 2;
  const int qs = (lane & 3) ^ ((rl >> 1) & 3);
  const size_t goff16 = (size_t)rl * 512 + (size_t)qs * 8;

  const int c = lane & 15;
  const int g = lane >> 4;

  int aoff[4], boff[4];
  #pragma unroll
  for (int i = 0; i < 4; ++i) {
    const int rowa = wr * 64 + i * 16 + c;
    aoff[i] = rowa * 32 + ((g ^ ((rowa >> 1) & 3)) * 8);
    const int rowb = wc * 64 + i * 16 + c;
    boff[i] = rowb * 32 + ((g ^ ((rowb >> 1) & 3)) * 8);
  }

  f32x4 acc[4][4];
  #pragma unroll
  for (int i = 0; i < 4; ++i)
    #pragma unroll
    for (int j = 0; j < 4; ++j) acc[i][j] = (f32x4){0.f, 0.f, 0.f, 0.f};

  float4 areg[2][2];

#define LOAD_A32(k0) do { if (CVT_A) {                                         \
    _Pragma("unroll")                                                          \
    for (int ii = 0; ii < 2; ++ii) {                                           \
      const int s = wid * 2 + ii;                                              \
      const float* ga = Ag32 + (size_t)(s * 16 + rl) * 512 + (size_t)(k0)      \
                        + (size_t)qs * 8;                                      \
      areg[ii][0] = *(const float4*)ga;                                        \
      areg[ii][1] = *(const float4*)(ga + 4);                                  \
    } } } while (0)

#define WRITE_A(buf) do { if (CVT_A) {                                         \
    _Pragma("unroll")                                                          \
    for (int ii = 0; ii < 2; ++ii) {                                           \
      const int s = wid * 2 + ii;                                              \
      const float* ap = (const float*)&areg[ii][0];                            \
      f16x8 hv;                                                                \
      _Pragma("unroll")                                                        \
      for (int j = 0; j < 8; ++j) hv[j] = (f16)ap[j];                          \
      *(f16x8*)&lds[buf][0][(size_t)s * 512 + (size_t)lane * 8] = hv;          \
    } } } while (0)

#define STAGE_A16(buf, k0) do { if (!CVT_A) {                                  \
    _Pragma("unroll")                                                          \
    for (int ii = 0; ii < 2; ++ii) {                                           \
      const int s = wid * 2 + ii;                                              \
      const f16* ga = Ag16 + (size_t)s * 16 * 512 + (size_t)(k0) + goff16;     \
      __builtin_amdgcn_global_load_lds(                                        \
          (const __attribute__((address_space(1))) void*)ga,                   \
          (__attribute__((address_space(3))) void*)&lds[buf][0][s * 512],      \
          16, 0, 0);                                                           \
    } } } while (0)

#define STAGE_B(buf, k0) do {                                                  \
    _Pragma("unroll")                                                          \
    for (int ii = 0; ii < 2; ++ii) {                                           \
      const int s = wid * 2 + ii;                                              \
      const f16* gb = Bg + (size_t)s * 16 * 512 + (size_t)(k0) + goff16;       \
      __builtin_amdgcn_global_load_lds(                                        \
          (const __attribute__((address_space(1))) void*)gb,                   \
          (__attribute__((address_space(3))) void*)&lds[buf][1][s * 512],      \
          16, 0, 0);                                                           \
    } } while (0)

  LOAD_A32(0); STAGE_A16(0, 0); STAGE_B(0, 0); WRITE_A(0);
  __syncthreads();

  for (int t = 0; t < 16; ++t) {
    const int cur = t & 1;
    if (t < 15) { LOAD_A32((t + 1) * 32); STAGE_A16(cur ^ 1, (t + 1) * 32);
                  STAGE_B(cur ^ 1, (t + 1) * 32); }
    f16x8 af[4], bf[4];
    #pragma unroll
    for (int i = 0; i < 4; ++i) {
      af[i] = *(const f16x8*)&lds[cur][0][aoff[i]];
      bf[i] = *(const f16x8*)&lds[cur][1][boff[i]];
    }
    #pragma unroll
    for (int mi = 0; mi < 4; ++mi)
      #pragma unroll
      for (int ni = 0; ni < 4; ++ni)
        acc[mi][ni] = __builtin_amdgcn_mfma_f32_16x16x32_f16(
            af[mi], bf[ni], acc[mi][ni], 0, 0, 0);
    if (t < 15) WRITE_A(cur ^ 1);
    __syncthreads();
  }
#undef LOAD_A32
#undef WRITE_A
#undef STAGE_A16
#undef STAGE_B

  const int col_base = (int)n0 + wc * 64;
  const int row_base = (int)m0 + wr * 64 + g * 4;
  float bv[4];
  #pragma unroll
  for (int ni = 0; ni < 4; ++ni) bv[ni] = Bi[col_base + ni * 16 + c];
  #pragma unroll
  for (int mi = 0; mi < 4; ++mi)
    #pragma unroll
    for (int ni = 0; ni < 4; ++ni)
      #pragma unroll
      for (int r = 0; r < 4; ++r) {
        const size_t row = (size_t)(row_base + mi * 16 + r);
        O[row * 512 + col_base + ni * 16 + c] = (OutT)(acc[mi][ni][r] + bv[ni]);
      }
}

// ---------------------------------------------------------------------------
// MFMA windowed attention. One WAVE per (b,h,wi,wj); 4 waves/block.
// S^T = K*Q^T via 16x16x32 MFMA, frags direct from global (head-major layout:
// channel = h*32+e, so a token's 32 head-channels are contiguous).
// C-layout (m89): lane(g,c) reg r of acc_s[mt][kt] = S^T[k=mt*16+4g+r][q=kt*16+c].
// Softmax per q-column: 16 in-lane + shfl_xor(16,32). P (f32, normalized)
// -> f16 -> Pl[q][kv] per-wave LDS slice -> A-frags for PV MFMA.
// V B-frags gathered direct from global (u16). No __syncthreads except pesh.
// ---------------------------------------------------------------------------
__global__ __launch_bounds__(256) void attn_kernel(
    const f16* __restrict__ cq, const f16* __restrict__ ck,
    const f16* __restrict__ vs, const f16* __restrict__ vh,
    const float* __restrict__ pe, f16* __restrict__ osc, f16* __restrict__ osh) {
  __shared__ f16 Pl[4][64][72];     // per-wave P[q][kv], stride 144B (16B mult)
  __shared__ float pesh[228];

  const int tid = threadIdx.x;
  for (int i = tid; i < 225; i += 256) pesh[i] = pe[i];
  __syncthreads();                  // only barrier (pesh shared per block)

  const int wid = tid >> 6;
  const int lane = tid & 63;
  const int g = lane >> 4;          // 0..3
  const int c = lane & 15;          // 0..15
  const int w = blockIdx.x * 4 + wid;
  const int wj = w & 7;
  const int wi = (w >> 3) & 7;
  const int h  = (w >> 6) & 15;
  const int b  = w >> 10;

  // ---- QK^T (S^T = K·Q^T): A-frag = K tile mt, B-frag = Q tile kt ----
  // frag lane(g,c): token i*16+c, elems g*8..g*8+7; roll(-4,-4) folded in.
  size_t taddr[4];
  #pragma unroll
  for (int i = 0; i < 4; ++i) {
    const int ty = (wi * 8 + i * 2 + (c >> 3) + 4) & 63;
    const int tx = (wj * 8 + (c & 7) + 4) & 63;
    taddr[i] = ((size_t)b * NTOK + ty * 64 + tx) * EMB + h * 32 + g * 8;
  }
  f16x8 kf[4], qf[4];
  #pragma unroll
  for (int i = 0; i < 4; ++i) {
    kf[i] = *(const f16x8*)(ck + taddr[i]);
    qf[i] = *(const f16x8*)(cq + taddr[i]);
  }

  f32x4 s[4][4];
  #pragma unroll
  for (int mt = 0; mt < 4; ++mt)
    #pragma unroll
    for (int kt = 0; kt < 4; ++kt) s[mt][kt] = (f32x4){0.f, 0.f, 0.f, 0.f};
  #pragma unroll
  for (int mt = 0; mt < 4; ++mt)
    #pragma unroll
    for (int kt = 0; kt < 4; ++kt)
      s[mt][kt] = __builtin_amdgcn_mfma_f32_16x16x32_f16(kf[mt], qf[kt],
                                                         s[mt][kt], 0, 0, 0);

  // ---- scale + pos_emb + masks.  q=kt*16+c, k=mt*16+4g+r ----
  const float invs = 0.17677669529663687f;  // 1/sqrt(32)
  const bool rm = (wi == 7);
  const bool cm = (wj == 7) && (((c >> 2) & 1) != (g & 1));  // lane-constant
  #pragma unroll
  for (int mt = 0; mt < 4; ++mt)
    #pragma unroll
    for (int kt = 0; kt < 4; ++kt) {
      const bool rmask = rm && ((mt >> 1) != (kt >> 1));     // acc-uniform
      const int ry = (mt - kt) * 2 + (g >> 1) - (c >> 3) + 7;
      #pragma unroll
      for (int r = 0; r < 4; ++r) {
        const int rx = (g & 1) * 4 + r - (c & 7) + 7;
        float d = s[mt][kt][r] * invs + pesh[ry * 15 + rx];
        if (rmask || cm) d = -1e30f;
        s[mt][kt][r] = d;
      }
    }

  // ---- softmax over k for each of the lane's 4 q's (q = kt*16+c) ----
  #pragma unroll
  for (int kt = 0; kt < 4; ++kt) {
    float m = -1e30f;
    #pragma unroll
    for (int mt = 0; mt < 4; ++mt)
      #pragma unroll
      for (int r = 0; r < 4; ++r) m = fmaxf(m, s[mt][kt][r]);
    m = fmaxf(m, __shfl_xor(m, 16));
    m = fmaxf(m, __shfl_xor(m, 32));
    float sum = 0.f;
    #pragma unroll
    for (int mt = 0; mt < 4; ++mt)
      #pragma unroll
      for (int r = 0; r < 4; ++r) {
        const float p = __expf(s[mt][kt][r] - m);
        s[mt][kt][r] = p;
        sum += p;
      }
    sum += __shfl_xor(sum, 16);
    sum += __shfl_xor(sum, 32);
    const float rs = 1.f / sum;
    #pragma unroll
    for (int mt = 0; mt < 4; ++mt)
      #pragma unroll
      for (int r = 0; r < 4; ++r) s[mt][kt][r] *= rs;
  }

  // ---- write P (f16) transposed to Pl[q][kv]: kv=mt*16+4g+r contiguous ----
  #pragma unroll
  for (int mt = 0; mt < 4; ++mt)
    #pragma unroll
    for (int kt = 0; kt < 4; ++kt) {
      f16x4 pk = {(f16)s[mt][kt][0], (f16)s[mt][kt][1],
                  (f16)s[mt][kt][2], (f16)s[mt][kt][3]};
      *(f16x4*)&Pl[wid][kt * 16 + c][mt * 16 + g * 4] = pk;
    }

  // ---- V B-frags direct from global: elem j = V[kv=ks*32+g*8+j][e=nt*16+c] ----
  size_t vb[2];
  #pragma unroll
  for (int ks = 0; ks < 2; ++ks) {
    const int vy = (wi * 8 + ks * 4 + g + 4) & 63;
    vb[ks] = ((size_t)b * NTOK + vy * 64) * EMB + h * 32 + c;
  }
  int xo[8];
  #pragma unroll
  for (int j = 0; j < 8; ++j) xo[j] = ((wj * 8 + j + 4) & 63) * EMB;

  f16x8 vfs[2][2], vfh[2][2];   // [nt][ks]
  #pragma unroll
  for (int nt = 0; nt < 2; ++nt)
    #pragma unroll
    for (int ks = 0; ks < 2; ++ks)
      #pragma unroll
      for (int j = 0; j < 8; ++j) {
        const size_t a = vb[ks] + xo[j] + nt * 16;
        vfs[nt][ks][j] = vs[a];
        vfh[nt][ks][j] = vh[a];
      }

  // ---- A-frags from Pl: row mt*16+c, cols ks*32+g*8.. (16B aligned) ----
  f16x8 af[4][2];
  #pragma unroll
  for (int mt = 0; mt < 4; ++mt)
    #pragma unroll
    for (int ks = 0; ks < 2; ++ks)
      af[mt][ks] = *(const f16x8*)&Pl[wid][mt * 16 + c][ks * 32 + g * 8];

  // ---- PV + store. D[q=mt*16+4g+r][e=nt*16+c]; np has no roll-back ----
  size_t ob[4];
  #pragma unroll
  for (int mt = 0; mt < 4; ++mt) {
    const int np = (wi * 8 + 2 * mt + (g >> 1)) * 64 + wj * 8 + 4 * (g & 1);
    ob[mt] = ((size_t)b * NTOK + np) * EMB + h * 32 + c;
  }

  {
    f32x4 o[4][2];
    #pragma unroll
    for (int mt = 0; mt < 4; ++mt)
      #pragma unroll
      for (int nt = 0; nt < 2; ++nt) o[mt][nt] = (f32x4){0.f, 0.f, 0.f, 0.f};
    #pragma unroll
    for (int mt = 0; mt < 4; ++mt)
      #pragma unroll
      for (int nt = 0; nt < 2; ++nt)
        #pragma unroll
        for (int ks = 0; ks < 2; ++ks)
          o[mt][nt] = __builtin_amdgcn_mfma_f32_16x16x32_f16(
              af[mt][ks], vfs[nt][ks], o[mt][nt], 0, 0, 0);
    #pragma unroll
    for (int mt = 0; mt < 4; ++mt)
      #pragma unroll
      for (int nt = 0; nt < 2; ++nt)
        #pragma unroll
        for (int r = 0; r < 4; ++r)
          osc[ob[mt] + (size_t)r * EMB + nt * 16] = (f16)o[mt][nt][r];
  }
  {
    f32x4 o[4][2];
    #pragma unroll
    for (int mt = 0; mt < 4; ++mt)
      #pragma unroll
      for (int nt = 0; nt < 2; ++nt) o[mt][nt] = (f32x4){0.f, 0.f, 0.f, 0.f};
    #pragma unroll
    for (int mt = 0; mt < 4; ++mt)
      #pragma unroll
      for (int nt = 0; nt < 2; ++nt)
        #pragma unroll
        for (int ks = 0; ks < 2; ++ks)
          o[mt][nt] = __builtin_amdgcn_mfma_f32_16x16x32_f16(
              af[mt][ks], vfh[nt][ks], o[mt][nt], 0, 0, 0);
    #pragma unroll
    for (int mt = 0; mt < 4; ++mt)
      #pragma unroll
      for (int nt = 0; nt < 2; ++nt)
        #pragma unroll
        for (int r = 0; r < 4; ++r)
          osh[ob[mt] + (size_t)r * EMB + nt * 16] = (f16)o[mt][nt][r];
  }
}

// ---------------------------------------------------------------------------
extern "C" void kernel_launch(void* const* d_in, const int* in_sizes, int n_in,
                              void* d_out, int out_size, void* d_ws, size_t ws_size,
                              hipStream_t stream) {
  const float* content = (const float*)d_in[0];
  const float* style   = (const float*)d_in[1];
  const float* scalex  = (const float*)d_in[2];
  const float* shiftx  = (const float*)d_in[3];
  const float* W1  = (const float*)d_in[4];  const float* b1  = (const float*)d_in[5];
  const float* W2  = (const float*)d_in[6];  const float* b2  = (const float*)d_in[7];
  const float* Wsc = (const float*)d_in[8];  const float* bsc = (const float*)d_in[9];
  const float* Wsh = (const float*)d_in[10]; const float* bsh = (const float*)d_in[11];
  const float* Wso = (const float*)d_in[12]; const float* bso = (const float*)d_in[13];
  const float* Wsho= (const float*)d_in[14]; const float* bsho= (const float*)d_in[15];
  const float* pos = (const float*)d_in[16];
  float* out = (float*)d_out;

  // workspace: Wh(6x262144 f16) | bp(2048 f32) | Ph(4xNELEM f16) | Oh(2xNELEM f16)
  f16* Wh = (f16*)d_ws;
  float* bp = (float*)(Wh + 6 * 262144);
  f16* Ph = (f16*)(bp + 2048);
  f16* Oh = Ph + 4 * NELEM;

  // 1) convert weights (P1 rows permuted to head-major) + biases
  CvtW CW;
  CW.w[0] = W1; CW.w[1] = W2; CW.w[2] = Wsc; CW.w[3] = Wsh; CW.w[4] = Wso; CW.w[5] = Wsho;
  CW.b[0] = b1; CW.b[1] = b2; CW.b[2] = bsc; CW.b[3] = bsh;
  for (int i = 0; i < 6; ++i) CW.out[i] = Wh + (size_t)i * 262144;
  CW.bp = bp;
  hipLaunchKernelGGL(cvt_w, dim3(512, 6), dim3(128), 0, stream, CW);

  // 2) input projections: fp32 A converted in-staging, f16 head-major out
  GemmF16 P1;
  P1.X[0] = content; P1.X[1] = style; P1.X[2] = scalex; P1.X[3] = shiftx;
  for (int i = 0; i < 4; ++i) {
    P1.W[i] = Wh + (size_t)i * 262144;
    P1.Bi[i] = bp + i * 512;
    P1.O[i] = Ph + (size_t)i * NELEM;
  }
  hipLaunchKernelGGL(HIP_KERNEL_NAME(gemm_mfma<true, f16>),
                     dim3(M_TOT / 128, EMB / 128, 4), dim3(256), 0, stream, P1);

  // 3) attention: 8192 window-heads, 1 wave each, 4 waves/block
  hipLaunchKernelGGL(attn_kernel, dim3(BSZ * HEADS * WN * WN / 4), dim3(256), 0,
                     stream, Ph, Ph + NELEM, Ph + 2 * NELEM, Ph + 3 * NELEM, pos,
                     Oh, Oh + NELEM);

  // 4) output projections (f16 A via global_load_lds, fp32 out -> d_out)
  GemmF16 P2;
  P2.X[0] = Oh;          P2.W[0] = Wh + 4 * 262144; P2.Bi[0] = bso;  P2.O[0] = out;
  P2.X[1] = Oh + NELEM;  P2.W[1] = Wh + 5 * 262144; P2.Bi[1] = bsho; P2.O[1] = out + NELEM;
  P2.X[2] = P2.X[0]; P2.W[2] = P2.W[0]; P2.Bi[2] = P2.Bi[0]; P2.O[2] = P2.O[0];
  P2.X[3] = P2.X[1]; P2.W[3] = P2.W[1]; P2.Bi[3] = P2.Bi[1]; P2.O[3] = P2.O[1];
  hipLaunchKernelGGL(HIP_KERNEL_NAME(gemm_mfma<false, float>),
                     dim3(M_TOT / 128, EMB / 128, 2), dim3(256), 0, stream, P2);
}